// Round 1
// baseline (52.660 us; speedup 1.0000x reference)
//
#include <hip/hip_runtime.h>

// RegionAttention: bin 8M landmarks into a 512x512 grid, output
// out[i] = enhanced_weight[i] if any landmark falls in bin i else 1.0f.
//
// image_size = 8192, patch = 16 -> c = min(floor(x/16), 511), r = min(floor(y/16), 511)
// x*0.0625f is an exact fp32 op (power-of-two scale), truncation == floor for x >= 0,
// so bin indices are bit-identical to the JAX reference.

#define N_LANDMARKS 8388608
#define N_BINS      262144   // 512*512
#define GRID_COLS   512

// --- path A (uses d_ws flags) -------------------------------------------------

__global__ void scatter_flags_kernel(const float4* __restrict__ lm2,
                                     unsigned char* __restrict__ flags,
                                     int n4) {
    int i = blockIdx.x * blockDim.x + threadIdx.x;
    const int stride = gridDim.x * blockDim.x;
    for (; i < n4; i += stride) {
        float4 v = lm2[i];              // two landmarks: (x0,y0,x1,y1)
        int c0 = min((int)(v.x * 0.0625f), GRID_COLS - 1);
        int r0 = min((int)(v.y * 0.0625f), GRID_COLS - 1);
        int c1 = min((int)(v.z * 0.0625f), GRID_COLS - 1);
        int r1 = min((int)(v.w * 0.0625f), GRID_COLS - 1);
        flags[r0 * GRID_COLS + c0] = (unsigned char)1;
        flags[r1 * GRID_COLS + c1] = (unsigned char)1;
    }
}

__global__ void blend_kernel(const unsigned char* __restrict__ flags,
                             const float* __restrict__ ew,
                             float* __restrict__ out) {
    int i = blockIdx.x * blockDim.x + threadIdx.x;   // exactly N_BINS threads
    out[i] = flags[i] ? ew[i] : 1.0f;
}

// --- path B (fallback if ws too small: direct scatter into out) --------------

__global__ void init_out_kernel(float* __restrict__ out) {
    int i = blockIdx.x * blockDim.x + threadIdx.x;
    out[i] = 1.0f;
}

__global__ void scatter_direct_kernel(const float4* __restrict__ lm2,
                                      const float* __restrict__ ew,
                                      float* __restrict__ out,
                                      int n4) {
    int i = blockIdx.x * blockDim.x + threadIdx.x;
    const int stride = gridDim.x * blockDim.x;
    for (; i < n4; i += stride) {
        float4 v = lm2[i];
        int c0 = min((int)(v.x * 0.0625f), GRID_COLS - 1);
        int r0 = min((int)(v.y * 0.0625f), GRID_COLS - 1);
        int c1 = min((int)(v.z * 0.0625f), GRID_COLS - 1);
        int r1 = min((int)(v.w * 0.0625f), GRID_COLS - 1);
        int i0 = r0 * GRID_COLS + c0;
        int i1 = r1 * GRID_COLS + c1;
        out[i0] = ew[i0];               // duplicate same-value writes are benign
        out[i1] = ew[i1];
    }
}

extern "C" void kernel_launch(void* const* d_in, const int* in_sizes, int n_in,
                              void* d_out, int out_size, void* d_ws, size_t ws_size,
                              hipStream_t stream) {
    const float4* lm2 = (const float4*)d_in[0];          // landmarks (N,2) -> N/2 float4
    const float*  ew  = (const float*)d_in[1];           // enhanced_weight (N_BINS,)
    float* out        = (float*)d_out;                   // (N_BINS,) float32

    const int n4 = N_LANDMARKS / 2;                      // 4,194,304 float4 elements

    const int BLK = 256;
    const int SCATTER_BLOCKS = 2048;                     // grid-stride, ~8 iters/thread

    if (ws_size >= (size_t)N_BINS) {
        unsigned char* flags = (unsigned char*)d_ws;
        hipMemsetAsync(flags, 0, N_BINS, stream);
        scatter_flags_kernel<<<SCATTER_BLOCKS, BLK, 0, stream>>>(lm2, flags, n4);
        blend_kernel<<<N_BINS / BLK, BLK, 0, stream>>>(flags, ew, out);
    } else {
        init_out_kernel<<<N_BINS / BLK, BLK, 0, stream>>>(out);
        scatter_direct_kernel<<<SCATTER_BLOCKS, BLK, 0, stream>>>(lm2, ew, out, n4);
    }
}

// Round 2
// 25.011 us; speedup vs baseline: 2.1055x; 2.1055x over previous
//
#include <hip/hip_runtime.h>

// RegionAttention: bin 8M landmarks into a 512x512 grid; out[i] = enhanced[i]
// if any landmark falls in bin i else 1.0f.
//
// Round-2 structure: global scattered byte-stores (the round-1 bottleneck:
// ~4 cyc per scattered lane-store in the TA/L2) are replaced by per-block
// LDS bitmasks (32 KB = 262144 bins / 8). Each block ORs landmarks into LDS
// (ds_or, bank-conflict cost hidden under the 64 MB load stream), then dumps
// its mask coalesced to a per-block region in d_ws. A second kernel ORs the
// 256 regions and blends with enhanced_weight, fully writing d_out.

#define N_LANDMARKS 8388608
#define N_BINS      262144            // 512*512
#define GRID_COLS   512
#define NWORDS      (N_BINS / 32)     // 8192 dwords = 32 KB bitmask
#define P1_BLOCKS   256
#define P1_THREADS  1024

// --- pass 1: bin into per-block LDS bitmask, dump coalesced ------------------

__global__ __launch_bounds__(P1_THREADS)
void bin_lds_kernel(const float4* __restrict__ lm2,
                    unsigned int* __restrict__ regions) {
    __shared__ unsigned int mask[NWORDS];
    const int tid = threadIdx.x;

    #pragma unroll
    for (int w = tid; w < NWORDS; w += P1_THREADS) mask[w] = 0u;
    __syncthreads();

    const int total = P1_BLOCKS * P1_THREADS;          // 262144 threads
    const int n4 = N_LANDMARKS / 2;                    // 4194304 float4s -> 16 iters
    int i = blockIdx.x * P1_THREADS + tid;
    #pragma unroll 4
    for (; i < n4; i += total) {
        float4 v = lm2[i];                             // (x0,y0,x1,y1)
        int c0 = min((int)(v.x * 0.0625f), GRID_COLS - 1);
        int r0 = min((int)(v.y * 0.0625f), GRID_COLS - 1);
        int c1 = min((int)(v.z * 0.0625f), GRID_COLS - 1);
        int r1 = min((int)(v.w * 0.0625f), GRID_COLS - 1);
        unsigned int i0 = (unsigned int)(r0 * GRID_COLS + c0);
        unsigned int i1 = (unsigned int)(r1 * GRID_COLS + c1);
        atomicOr(&mask[i0 >> 5], 1u << (i0 & 31));     // ds_or_b32, no return
        atomicOr(&mask[i1 >> 5], 1u << (i1 & 31));
    }
    __syncthreads();

    unsigned int* dst = regions + (size_t)blockIdx.x * NWORDS;
    #pragma unroll
    for (int w = tid; w < NWORDS; w += P1_THREADS) dst[w] = mask[w];
}

// --- pass 2: OR the 256 regions, blend with enhanced_weight ------------------
// 8192 threads, one per bitmask word; each writes 32 consecutive outputs.

__global__ __launch_bounds__(64)
void merge_blend_kernel(const unsigned int* __restrict__ regions,
                        const float4* __restrict__ ew4,
                        float4* __restrict__ out4) {
    const int w = blockIdx.x * 64 + threadIdx.x;       // 0..8191
    unsigned int m = 0u;
    #pragma unroll 8
    for (int b = 0; b < P1_BLOCKS; ++b)
        m |= regions[(size_t)b * NWORDS + w];

    #pragma unroll
    for (int k = 0; k < 8; ++k) {                      // bins 32w+4k .. 32w+4k+3
        float4 e = ew4[w * 8 + k];
        float4 r;
        r.x = ((m >> (k * 4 + 0)) & 1u) ? e.x : 1.0f;
        r.y = ((m >> (k * 4 + 1)) & 1u) ? e.y : 1.0f;
        r.z = ((m >> (k * 4 + 2)) & 1u) ? e.z : 1.0f;
        r.w = ((m >> (k * 4 + 3)) & 1u) ? e.w : 1.0f;
        out4[w * 8 + k] = r;
    }
}

// --- fallback (small ws): round-1 byte-flag path ------------------------------

__global__ void scatter_flags_kernel(const float4* __restrict__ lm2,
                                     unsigned char* __restrict__ flags, int n4) {
    int i = blockIdx.x * blockDim.x + threadIdx.x;
    const int stride = gridDim.x * blockDim.x;
    for (; i < n4; i += stride) {
        float4 v = lm2[i];
        int c0 = min((int)(v.x * 0.0625f), GRID_COLS - 1);
        int r0 = min((int)(v.y * 0.0625f), GRID_COLS - 1);
        int c1 = min((int)(v.z * 0.0625f), GRID_COLS - 1);
        int r1 = min((int)(v.w * 0.0625f), GRID_COLS - 1);
        flags[r0 * GRID_COLS + c0] = (unsigned char)1;
        flags[r1 * GRID_COLS + c1] = (unsigned char)1;
    }
}

__global__ void blend_kernel(const unsigned char* __restrict__ flags,
                             const float* __restrict__ ew,
                             float* __restrict__ out) {
    int i = blockIdx.x * blockDim.x + threadIdx.x;
    out[i] = flags[i] ? ew[i] : 1.0f;
}

extern "C" void kernel_launch(void* const* d_in, const int* in_sizes, int n_in,
                              void* d_out, int out_size, void* d_ws, size_t ws_size,
                              hipStream_t stream) {
    const float4* lm2 = (const float4*)d_in[0];
    const float*  ew  = (const float*)d_in[1];
    float* out        = (float*)d_out;

    const size_t regions_bytes = (size_t)P1_BLOCKS * NWORDS * sizeof(unsigned int); // 8 MB

    if (ws_size >= regions_bytes) {
        unsigned int* regions = (unsigned int*)d_ws;
        bin_lds_kernel<<<P1_BLOCKS, P1_THREADS, 0, stream>>>(lm2, regions);
        merge_blend_kernel<<<NWORDS / 64, 64, 0, stream>>>(
            regions, (const float4*)ew, (float4*)out);
    } else if (ws_size >= (size_t)N_BINS) {
        unsigned char* flags = (unsigned char*)d_ws;
        hipMemsetAsync(flags, 0, N_BINS, stream);
        scatter_flags_kernel<<<2048, 256, 0, stream>>>(lm2, flags, N_LANDMARKS / 2);
        blend_kernel<<<N_BINS / 256, 256, 0, stream>>>(flags, ew, out);
    } else {
        // last resort: direct scatter into out after init
        // (not expected; ws is normally generous)
        hipMemsetAsync(out, 0, 0, stream);  // no-op keep structure deterministic
        scatter_flags_kernel<<<2048, 256, 0, stream>>>(lm2, (unsigned char*)d_out, 0);
        blend_kernel<<<N_BINS / 256, 256, 0, stream>>>((unsigned char*)d_out, ew, out);
    }
}

// Round 3
// 20.182 us; speedup vs baseline: 2.6093x; 1.2393x over previous
//
#include <hip/hip_runtime.h>

// RegionAttention: bin 8M landmarks into a 512x512 grid; out[i] = enhanced[i]
// if any landmark falls in bin i else 1.0f.
//
// Structure (round 3):
//  pass 1: 256 blocks x 1024 thr, one per CU. Per-block 32 KB LDS bitmask
//          (262144 bins / 8) built with ds_or atomics; dumped coalesced to a
//          per-block region in d_ws (8 MB total). Global scattered stores: none.
//  pass 2: 256 blocks x 256 thr. Per block: 32 words x 256 regions OR-reduce,
//          split 8 ways across thread groups (32 regions/thread, unrolled for
//          MLP), LDS reduce, then blend 256 float4 with enhanced_weight.
//          (Round-2 merge had only 8192 threads -> latency-bound; this is 16x.)

#define N_LANDMARKS 8388608
#define N_BINS      262144            // 512*512
#define GRID_COLS   512
#define NWORDS      (N_BINS / 32)     // 8192 dwords = 32 KB bitmask
#define P1_BLOCKS   256
#define P1_THREADS  1024

// --- pass 1: bin into per-block LDS bitmask, dump coalesced ------------------

__global__ __launch_bounds__(P1_THREADS)
void bin_lds_kernel(const float4* __restrict__ lm2,
                    unsigned int* __restrict__ regions) {
    __shared__ unsigned int mask[NWORDS];
    const int tid = threadIdx.x;

    #pragma unroll
    for (int w = tid; w < NWORDS; w += P1_THREADS) mask[w] = 0u;
    __syncthreads();

    const int total = P1_BLOCKS * P1_THREADS;          // 262144 threads
    const int n4 = N_LANDMARKS / 2;                    // 4194304 float4s -> 16 iters
    int i = blockIdx.x * P1_THREADS + tid;
    #pragma unroll 8
    for (; i < n4; i += total) {
        float4 v = lm2[i];                             // (x0,y0,x1,y1)
        int c0 = min((int)(v.x * 0.0625f), GRID_COLS - 1);
        int r0 = min((int)(v.y * 0.0625f), GRID_COLS - 1);
        int c1 = min((int)(v.z * 0.0625f), GRID_COLS - 1);
        int r1 = min((int)(v.w * 0.0625f), GRID_COLS - 1);
        unsigned int i0 = (unsigned int)(r0 * GRID_COLS + c0);
        unsigned int i1 = (unsigned int)(r1 * GRID_COLS + c1);
        atomicOr(&mask[i0 >> 5], 1u << (i0 & 31));     // ds_or_b32, no return
        atomicOr(&mask[i1 >> 5], 1u << (i1 & 31));
    }
    __syncthreads();

    unsigned int* dst = regions + (size_t)blockIdx.x * NWORDS;
    #pragma unroll
    for (int w = tid; w < NWORDS; w += P1_THREADS) dst[w] = mask[w];
}

// --- pass 2: OR the 256 regions (8-way split), blend with enhanced_weight ----
// 256 blocks x 256 threads. Block owns 32 bitmask words = 1024 bins = 256 float4.

__global__ __launch_bounds__(256)
void merge_blend_kernel(const unsigned int* __restrict__ regions,
                        const float4* __restrict__ ew4,
                        float4* __restrict__ out4) {
    __shared__ unsigned int part[8][33];               // +1 pad: conflict-free reduce
    __shared__ unsigned int merged[32];

    const int t   = threadIdx.x;
    const int wl  = t & 31;                            // word within block
    const int seg = t >> 5;                            // region segment, 0..7
    const int w   = blockIdx.x * 32 + wl;              // global word index

    // OR 32 regions for this word; lanes wl=0..31 read 128B contiguous per region.
    const unsigned int* p = regions + (size_t)seg * 32 * NWORDS + w;
    unsigned int m = 0u;
    #pragma unroll
    for (int b = 0; b < 32; ++b)
        m |= p[(size_t)b * NWORDS];
    part[seg][wl] = m;
    __syncthreads();

    if (t < 32) {
        unsigned int mm = part[0][t];
        #pragma unroll
        for (int s = 1; s < 8; ++s) mm |= part[s][t];
        merged[t] = mm;
    }
    __syncthreads();

    // blend: thread t -> float4 t of this block (bins 4t..4t+3 local)
    const int g4 = blockIdx.x * 256 + t;
    const unsigned int mw = merged[t >> 3];
    const int sh = (t & 7) * 4;
    float4 e = ew4[g4];
    float4 r;
    r.x = ((mw >> (sh + 0)) & 1u) ? e.x : 1.0f;
    r.y = ((mw >> (sh + 1)) & 1u) ? e.y : 1.0f;
    r.z = ((mw >> (sh + 2)) & 1u) ? e.z : 1.0f;
    r.w = ((mw >> (sh + 3)) & 1u) ? e.w : 1.0f;
    out4[g4] = r;
}

// --- fallback (small ws): byte-flag path --------------------------------------

__global__ void scatter_flags_kernel(const float4* __restrict__ lm2,
                                     unsigned char* __restrict__ flags, int n4) {
    int i = blockIdx.x * blockDim.x + threadIdx.x;
    const int stride = gridDim.x * blockDim.x;
    for (; i < n4; i += stride) {
        float4 v = lm2[i];
        int c0 = min((int)(v.x * 0.0625f), GRID_COLS - 1);
        int r0 = min((int)(v.y * 0.0625f), GRID_COLS - 1);
        int c1 = min((int)(v.z * 0.0625f), GRID_COLS - 1);
        int r1 = min((int)(v.w * 0.0625f), GRID_COLS - 1);
        flags[r0 * GRID_COLS + c0] = (unsigned char)1;
        flags[r1 * GRID_COLS + c1] = (unsigned char)1;
    }
}

__global__ void blend_kernel(const unsigned char* __restrict__ flags,
                             const float* __restrict__ ew,
                             float* __restrict__ out) {
    int i = blockIdx.x * blockDim.x + threadIdx.x;
    out[i] = flags[i] ? ew[i] : 1.0f;
}

extern "C" void kernel_launch(void* const* d_in, const int* in_sizes, int n_in,
                              void* d_out, int out_size, void* d_ws, size_t ws_size,
                              hipStream_t stream) {
    const float4* lm2 = (const float4*)d_in[0];
    const float*  ew  = (const float*)d_in[1];
    float* out        = (float*)d_out;

    const size_t regions_bytes = (size_t)P1_BLOCKS * NWORDS * sizeof(unsigned int); // 8 MB

    if (ws_size >= regions_bytes) {
        unsigned int* regions = (unsigned int*)d_ws;
        bin_lds_kernel<<<P1_BLOCKS, P1_THREADS, 0, stream>>>(lm2, regions);
        merge_blend_kernel<<<NWORDS / 32, 256, 0, stream>>>(
            regions, (const float4*)ew, (float4*)out);
    } else {
        unsigned char* flags = (unsigned char*)d_ws;
        hipMemsetAsync(flags, 0, N_BINS, stream);
        scatter_flags_kernel<<<2048, 256, 0, stream>>>(lm2, flags, N_LANDMARKS / 2);
        blend_kernel<<<N_BINS / 256, 256, 0, stream>>>(flags, ew, out);
    }
}